// Round 1
// baseline (373.440 us; speedup 1.0000x reference)
//
#include <hip/hip_runtime.h>

// GLOBE_61864708931733: T=2048 targets x S=512 sources; per-pair 7-feat
// geometry -> MLP 7->64->64->64->3 (tanh) -> decay-weighted reduction over S.
// Round 1: fp32 VALU baseline. Wave = 1 target, lane = source-in-chunk.
// Activations staged through per-thread LDS column (static reg indexing for
// the unrolled j-loop, rolled i-loop); weights via wave-uniform loads
// (expect s_load + v_fmac v,s,v).

#define N_T   2048
#define N_S   512
#define F_IN  7
#define H     64
#define BLK   128              // 2 waves per block
#define WPB   (BLK / 64)       // waves (targets) per block

__device__ __forceinline__ float fast_rcp(float x) { return __builtin_amdgcn_rcpf(x); }
__device__ __forceinline__ float fast_rsq(float x) { return __builtin_amdgcn_rsqf(x); }

__device__ __forceinline__ float fast_tanh(float x) {
    // tanh(x) = 1 - 2/(exp(2x)+1); exact saturation at +-inf.
    float e = __expf(2.0f * x);
    return fmaf(-2.0f, fast_rcp(e + 1.0f), 1.0f);
}

__global__ __launch_bounds__(BLK) void globe_kernel(
    const float* __restrict__ pts,    // [T,3]
    const float* __restrict__ ctr,    // [S,3]
    const float* __restrict__ nrm,    // [S,3]
    const float* __restrict__ areas,  // [S]
    const float* __restrict__ rlen,   // [2]
    const float* __restrict__ W1, const float* __restrict__ b1,   // [7,64],[64]
    const float* __restrict__ W2, const float* __restrict__ b2,   // [64,64],[64]
    const float* __restrict__ W3, const float* __restrict__ b3,   // [64,64],[64]
    const float* __restrict__ Wout, const float* __restrict__ bout, // [64,3],[3]
    const float* __restrict__ p_scale, const float* __restrict__ p_bias,
    const float* __restrict__ v_scale, const float* __restrict__ v_bias,
    float* __restrict__ out)          // [T,4]
{
    // Per-thread activation column; each thread only touches act[*][tid],
    // so no __syncthreads needed. [i][tid] layout -> lane-contiguous, no
    // meaningful bank conflicts (2 lanes/bank is free on gfx950).
    __shared__ float act[H][BLK];

    const int tid  = threadIdx.x;
    const int lane = tid & 63;
    const int wv   = tid >> 6;
    const int t    = blockIdx.x * WPB + wv;

    const float px = pts[3 * t + 0];
    const float py = pts[3 * t + 1];
    const float pz = pts[3 * t + 2];
    const float rinvL0 = fast_rcp(rlen[0]);
    const float rinvL1 = fast_rcp(rlen[1]);

    float accp = 0.0f, avx = 0.0f, avy = 0.0f, avz = 0.0f;

    for (int chunk = 0; chunk < N_S / 64; ++chunk) {
        const int s = chunk * 64 + lane;
        const float cx = ctr[3 * s + 0], cy = ctr[3 * s + 1], cz = ctr[3 * s + 2];
        const float nx = nrm[3 * s + 0], ny = nrm[3 * s + 1], nz = nrm[3 * s + 2];
        const float ar = areas[s];

        // ---- features ----
        const float rvx = px - cx, rvy = py - cy, rvz = pz - cz;
        const float r2  = rvx * rvx + rvy * rvy + rvz * rvz;
        const float r2e = r2 + 1e-8f;
        const float rinv = fast_rsq(r2e);
        const float r    = r2e * rinv;            // sqrt(r2+eps)
        const float rhx = rvx * rinv, rhy = rvy * rinv, rhz = rvz * rinv;
        const float c  = rhx * nx + rhy * ny + rhz * nz;
        const float c2 = c * c;
        const float f0 = fast_rcp(fmaf(r, rinvL0, 1.0f));
        const float f1 = fast_rcp(fmaf(r, rinvL1, 1.0f));
        const float f2 = 1.0f;
        const float f3 = c;
        const float f4 = fmaf(1.5f, c2, -0.5f);
        const float f5 = c * fmaf(2.5f, c2, -1.5f);
        const float f6 = __logf(ar);
        const float f[F_IN] = {f0, f1, f2, f3, f4, f5, f6};

        float b[H];

        // ---- layer 1: feats(regs) @ W1 ----
        #pragma unroll
        for (int j = 0; j < H; ++j) b[j] = b1[j];
        #pragma unroll
        for (int i = 0; i < F_IN; ++i) {
            #pragma unroll
            for (int j = 0; j < H; ++j) b[j] = fmaf(f[i], W1[i * H + j], b[j]);
        }
        #pragma unroll
        for (int j = 0; j < H; ++j) act[j][tid] = fast_tanh(b[j]);

        // ---- layer 2 ----
        #pragma unroll
        for (int j = 0; j < H; ++j) b[j] = b2[j];
        #pragma unroll 2
        for (int i = 0; i < H; ++i) {
            const float a = act[i][tid];
            #pragma unroll
            for (int j = 0; j < H; ++j) b[j] = fmaf(a, W2[i * H + j], b[j]);
        }
        #pragma unroll
        for (int j = 0; j < H; ++j) act[j][tid] = fast_tanh(b[j]);

        // ---- layer 3 ----
        #pragma unroll
        for (int j = 0; j < H; ++j) b[j] = b3[j];
        #pragma unroll 2
        for (int i = 0; i < H; ++i) {
            const float a = act[i][tid];
            #pragma unroll
            for (int j = 0; j < H; ++j) b[j] = fmaf(a, W3[i * H + j], b[j]);
        }

        // ---- output layer: tanh(b) stays in regs ----
        float o0 = bout[0], o1 = bout[1], o2 = bout[2];
        #pragma unroll
        for (int j = 0; j < H; ++j) {
            const float tj = fast_tanh(b[j]);
            o0 = fmaf(tj, Wout[j * 3 + 0], o0);
            o1 = fmaf(tj, Wout[j * 3 + 1], o1);
            o2 = fmaf(tj, Wout[j * 3 + 2], o2);
        }

        // ---- decay-weighted accumulation ----
        const float decay = ar * fast_rcp(r2 + 1.0f);
        accp = fmaf(o0, decay, accp);
        avx  = fmaf(fmaf(o1, rhx, o2 * nx), decay, avx);
        avy  = fmaf(fmaf(o1, rhy, o2 * ny), decay, avy);
        avz  = fmaf(fmaf(o1, rhz, o2 * nz), decay, avz);
    }

    // ---- in-wave reduction over 64 lanes ----
    #pragma unroll
    for (int off = 32; off > 0; off >>= 1) {
        accp += __shfl_down(accp, off, 64);
        avx  += __shfl_down(avx,  off, 64);
        avy  += __shfl_down(avy,  off, 64);
        avz  += __shfl_down(avz,  off, 64);
    }

    if (lane == 0) {
        const float ps = p_scale[0], pb = p_bias[0];
        const float vs = v_scale[0], vb = v_bias[0];
        out[4 * t + 0] = fmaf(accp, ps, pb);
        out[4 * t + 1] = fmaf(avx, vs, vb);
        out[4 * t + 2] = fmaf(avy, vs, vb);
        out[4 * t + 3] = fmaf(avz, vs, vb);
    }
}

extern "C" void kernel_launch(void* const* d_in, const int* in_sizes, int n_in,
                              void* d_out, int out_size, void* d_ws, size_t ws_size,
                              hipStream_t stream) {
    (void)in_sizes; (void)n_in; (void)d_ws; (void)ws_size; (void)out_size;
    const float* pts   = (const float*)d_in[0];
    const float* ctr   = (const float*)d_in[1];
    const float* nrm   = (const float*)d_in[2];
    const float* areas = (const float*)d_in[3];
    const float* rlen  = (const float*)d_in[4];
    const float* W1    = (const float*)d_in[5];
    const float* b1    = (const float*)d_in[6];
    const float* W2    = (const float*)d_in[7];
    const float* b2    = (const float*)d_in[8];
    const float* W3    = (const float*)d_in[9];
    const float* b3    = (const float*)d_in[10];
    const float* Wout  = (const float*)d_in[11];
    const float* bout  = (const float*)d_in[12];
    const float* ps    = (const float*)d_in[13];
    const float* pb    = (const float*)d_in[14];
    const float* vs    = (const float*)d_in[15];
    const float* vb    = (const float*)d_in[16];

    dim3 grid(N_T / WPB), block(BLK);
    globe_kernel<<<grid, block, 0, stream>>>(
        pts, ctr, nrm, areas, rlen, W1, b1, W2, b2, W3, b3, Wout, bout,
        ps, pb, vs, vb, (float*)d_out);
}

// Round 3
// 173.855 us; speedup vs baseline: 2.1480x; 2.1480x over previous
//
#include <hip/hip_runtime.h>
#include <hip/hip_fp16.h>

// GLOBE_61864708931733 — R3: f16 MFMA + hi/lo-split weights.
// R2 failed absmax 1.125/0.81: weight bf16-rounding is SYSTEMATIC across the
// 512-source sum (same deltaW for every pair -> no cancellation). Fix:
//  - all weights split w = hi + lo (two f16), two MFMAs per product -> weights
//    effectively exact (2^-21), systematic term killed;
//  - activations/features in f16 (half-ulp 2^-11, 8x finer than bf16; their
//    rounding is pseudo-random across sources and cancels ~sqrt(512));
//  - RTN packing (no RTZ bias).
// Structure as R2: wave = 1 target, chunk = 64 sources, transposed GEMMs,
// A-frags (weights) VGPR-resident, activations round-trip a per-wave LDS slab,
// no __syncthreads. nt processed in 2 halves (acc 32 VGPR) to stay <256 VGPR.

#define N_T 2048
#define N_S 512
#define BLK 128
#define WPB 2

typedef _Float16 f16x8 __attribute__((ext_vector_type(8)));
typedef float f32x4 __attribute__((ext_vector_type(4)));
typedef unsigned short u16;
typedef unsigned int u32;

__device__ __forceinline__ f16x8 pack8h(const float t[8]) {
    union { f16x8 v; __half2 h2[4]; } p;
    p.h2[0] = __floats2half2_rn(t[0], t[1]);
    p.h2[1] = __floats2half2_rn(t[2], t[3]);
    p.h2[2] = __floats2half2_rn(t[4], t[5]);
    p.h2[3] = __floats2half2_rn(t[6], t[7]);
    return p.v;
}

__device__ __forceinline__ void split8(const float t[8], f16x8& hi, f16x8& lo) {
    float rh[8], rl[8];
    #pragma unroll
    for (int j = 0; j < 8; ++j) {
        float h = (float)(_Float16)t[j];   // RTN f32->f16->f32
        rh[j] = h;
        rl[j] = t[j] - h;                  // exact residual, fits f16
    }
    hi = pack8h(rh);
    lo = pack8h(rl);
}

__device__ __forceinline__ float fast_tanh(float x) {
    // tanh(x) = 1 - 2/(exp(2x)+1); exact saturation at +-inf.
#if __has_builtin(__builtin_amdgcn_exp2f)
    float e = __builtin_amdgcn_exp2f(x * 2.885390081777927f); // 2*log2(e)
#else
    float e = __expf(2.0f * x);
#endif
    return fmaf(-2.0f, __builtin_amdgcn_rcpf(e + 1.0f), 1.0f);
}

__device__ __forceinline__ f32x4 mfma16h(f16x8 a, f16x8 b, f32x4 c) {
    return __builtin_amdgcn_mfma_f32_16x16x32_f16(a, b, c, 0, 0, 0);
}

__device__ __forceinline__ void store4h(u16* dst, float t0, float t1, float t2, float t3) {
    __half2 ha = __floats2half2_rn(t0, t1);
    __half2 hb = __floats2half2_rn(t2, t3);
    uint2 w;
    w.x = *(u32*)&ha;
    w.y = *(u32*)&hb;
    *(uint2*)dst = w;
}

// One 64->64 tanh dense layer, hi/lo-split A, in-place via this wave's LDS slab.
// nt handled in halves {0,1},{2,3}: reads (pairs of the half) complete before
// writes (same pairs); the other half's rows are untouched -> no hazard.
__device__ __forceinline__ void dense_layer(const f16x8 whi[2][4], const f16x8 wlo[2][4],
                                            const float4* __restrict__ bv4,
                                            u16 (*hb)[72], int l15, int q) {
    #pragma unroll
    for (int nh = 0; nh < 2; ++nh) {
        f32x4 c[4][2];
        #pragma unroll
        for (int mt = 0; mt < 4; ++mt) {
            c[mt][0] = (f32x4){0.f, 0.f, 0.f, 0.f};
            c[mt][1] = (f32x4){0.f, 0.f, 0.f, 0.f};
        }
        #pragma unroll
        for (int ks = 0; ks < 2; ++ks) {
            const f16x8 bf0 = *(const f16x8*)&hb[(nh * 2 + 0) * 16 + l15][ks * 32 + q * 8];
            const f16x8 bf1 = *(const f16x8*)&hb[(nh * 2 + 1) * 16 + l15][ks * 32 + q * 8];
            #pragma unroll
            for (int mt = 0; mt < 4; ++mt) {
                c[mt][0] = mfma16h(whi[ks][mt], bf0, c[mt][0]);
                c[mt][1] = mfma16h(whi[ks][mt], bf1, c[mt][1]);
                c[mt][0] = mfma16h(wlo[ks][mt], bf0, c[mt][0]);
                c[mt][1] = mfma16h(wlo[ks][mt], bf1, c[mt][1]);
            }
        }
        #pragma unroll
        for (int mt = 0; mt < 4; ++mt) {
            const float4 bv = bv4[mt * 4 + q];    // bias[mt*16+q*4 .. +3]
            #pragma unroll
            for (int n = 0; n < 2; ++n) {
                store4h(&hb[(nh * 2 + n) * 16 + l15][mt * 16 + q * 4],
                        fast_tanh(c[mt][n][0] + bv.x),
                        fast_tanh(c[mt][n][1] + bv.y),
                        fast_tanh(c[mt][n][2] + bv.z),
                        fast_tanh(c[mt][n][3] + bv.w));
            }
        }
    }
}

__global__ __launch_bounds__(BLK, 2) void globe_mfma(
    const float* __restrict__ pts, const float* __restrict__ ctr,
    const float* __restrict__ nrm, const float* __restrict__ areas,
    const float* __restrict__ rlen,
    const float* __restrict__ W1, const float* __restrict__ b1,
    const float* __restrict__ W2, const float* __restrict__ b2,
    const float* __restrict__ W3, const float* __restrict__ b3,
    const float* __restrict__ Wout, const float* __restrict__ bout,
    const float* __restrict__ p_scale, const float* __restrict__ p_bias,
    const float* __restrict__ v_scale, const float* __restrict__ v_bias,
    float* __restrict__ out)
{
    __shared__ __align__(16) u16 hbuf[WPB][64][72];   // activations, row stride 144 B
    __shared__ __align__(16) float geom[WPB][64][12]; // decay,rhat | normal per pair
    __shared__ uint4 zbuf[WPB];                       // zero B-frag source (layer 1, q>0)

    const int tid  = threadIdx.x;
    const int lane = tid & 63;
    const int wv   = tid >> 6;
    const int l15  = lane & 15;
    const int q    = lane >> 4;
    const int t    = blockIdx.x * WPB + wv;

    if (lane == 0) zbuf[wv] = make_uint4(0u, 0u, 0u, 0u);

    // ---- stage weights into hi/lo A-fragment VGPRs (once) ----
    f16x8 w1hi[4], w1lo[4];
    f16x8 w2hi[2][4], w2lo[2][4], w3hi[2][4], w3lo[2][4];
    f16x8 wohi[2], wolo[2];
    {
        float tmp[8];
        #pragma unroll
        for (int mt = 0; mt < 4; ++mt) {          // W1aug: [m=64][k=8], row7 = b1
            const int m = mt * 16 + l15;
            if (q == 0) {
                #pragma unroll
                for (int j = 0; j < 7; ++j) tmp[j] = W1[j * 64 + m];
                tmp[7] = b1[m];
            } else {
                #pragma unroll
                for (int j = 0; j < 8; ++j) tmp[j] = 0.f;
            }
            split8(tmp, w1hi[mt], w1lo[mt]);
        }
        #pragma unroll
        for (int ks = 0; ks < 2; ++ks)
            #pragma unroll
            for (int mt = 0; mt < 4; ++mt) {
                const int m = mt * 16 + l15;
                #pragma unroll
                for (int j = 0; j < 8; ++j) tmp[j] = W2[(ks * 32 + q * 8 + j) * 64 + m];
                split8(tmp, w2hi[ks][mt], w2lo[ks][mt]);
            }
        #pragma unroll
        for (int ks = 0; ks < 2; ++ks)
            #pragma unroll
            for (int mt = 0; mt < 4; ++mt) {
                const int m = mt * 16 + l15;
                #pragma unroll
                for (int j = 0; j < 8; ++j) tmp[j] = W3[(ks * 32 + q * 8 + j) * 64 + m];
                split8(tmp, w3hi[ks][mt], w3lo[ks][mt]);
            }
        #pragma unroll
        for (int ks = 0; ks < 2; ++ks) {          // Wout^T: rows 0..2 live
            #pragma unroll
            for (int j = 0; j < 8; ++j)
                tmp[j] = (l15 < 3) ? Wout[(ks * 32 + q * 8 + j) * 3 + l15] : 0.f;
            split8(tmp, wohi[ks], wolo[ks]);
        }
    }

    const float px = pts[3 * t + 0], py = pts[3 * t + 1], pz = pts[3 * t + 2];
    const float invL0 = __builtin_amdgcn_rcpf(rlen[0]);
    const float invL1 = __builtin_amdgcn_rcpf(rlen[1]);
    const float bo0 = bout[0], bo1 = bout[1], bo2 = bout[2];

    const float4* __restrict__ b2v4 = (const float4*)b2;
    const float4* __restrict__ b3v4 = (const float4*)b3;
    u16 (*hb)[72] = hbuf[wv];

    float accp = 0.f, avx = 0.f, avy = 0.f, avz = 0.f;

    #pragma unroll 1
    for (int ch = 0; ch < N_S / 64; ++ch) {
        const int s = ch * 64 + lane;
        // ---- per-pair geometry + features (lane = pair) ----
        const float cx = ctr[3 * s + 0], cy = ctr[3 * s + 1], cz = ctr[3 * s + 2];
        const float nx = nrm[3 * s + 0], ny = nrm[3 * s + 1], nz = nrm[3 * s + 2];
        const float ar = areas[s];
        const float rvx = px - cx, rvy = py - cy, rvz = pz - cz;
        const float r2 = rvx * rvx + rvy * rvy + rvz * rvz;
        const float r2e = r2 + 1e-8f;
        const float rinv = __builtin_amdgcn_rsqf(r2e);
        const float r = r2e * rinv;
        const float rhx = rvx * rinv, rhy = rvy * rinv, rhz = rvz * rinv;
        const float cth = rhx * nx + rhy * ny + rhz * nz;
        const float c2 = cth * cth;
        float f[8];
        f[0] = __builtin_amdgcn_rcpf(fmaf(r, invL0, 1.0f));
        f[1] = __builtin_amdgcn_rcpf(fmaf(r, invL1, 1.0f));
        f[2] = 1.0f;
        f[3] = cth;
        f[4] = fmaf(1.5f, c2, -0.5f);
        f[5] = cth * fmaf(2.5f, c2, -1.5f);
        f[6] = __logf(ar);
        f[7] = 1.0f;                               // bias channel for layer 1
        const float decay = ar * __builtin_amdgcn_rcpf(r2 + 1.0f);

        *(f16x8*)&hb[lane][0] = pack8h(f);
        *(float4*)&geom[wv][lane][0] = make_float4(decay, rhx, rhy, rhz);
        *(float4*)&geom[wv][lane][4] = make_float4(nx, ny, nz, 0.f);

        // ---- layer 1 (K=32, octet 0 live; q>0 lanes read zeros) ----
        {
            const u16* zp = (const u16*)&zbuf[wv];
            #pragma unroll
            for (int nh = 0; nh < 2; ++nh) {
                f32x4 c1[4][2];
                #pragma unroll
                for (int mt = 0; mt < 4; ++mt) {
                    c1[mt][0] = (f32x4){0.f, 0.f, 0.f, 0.f};
                    c1[mt][1] = (f32x4){0.f, 0.f, 0.f, 0.f};
                }
                const u16* s0 = (q == 0) ? &hb[(nh * 2 + 0) * 16 + l15][0] : zp;
                const u16* s1 = (q == 0) ? &hb[(nh * 2 + 1) * 16 + l15][0] : zp;
                const f16x8 bf0 = *(const f16x8*)s0;
                const f16x8 bf1 = *(const f16x8*)s1;
                #pragma unroll
                for (int mt = 0; mt < 4; ++mt) {
                    c1[mt][0] = mfma16h(w1hi[mt], bf0, c1[mt][0]);
                    c1[mt][1] = mfma16h(w1hi[mt], bf1, c1[mt][1]);
                    c1[mt][0] = mfma16h(w1lo[mt], bf0, c1[mt][0]);
                    c1[mt][1] = mfma16h(w1lo[mt], bf1, c1[mt][1]);
                }
                #pragma unroll
                for (int mt = 0; mt < 4; ++mt)
                    #pragma unroll
                    for (int n = 0; n < 2; ++n) {
                        store4h(&hb[(nh * 2 + n) * 16 + l15][mt * 16 + q * 4],
                                fast_tanh(c1[mt][n][0]), fast_tanh(c1[mt][n][1]),
                                fast_tanh(c1[mt][n][2]), fast_tanh(c1[mt][n][3]));
                    }
            }
        }

        // ---- layers 2, 3 ----
        dense_layer(w2hi, w2lo, b2v4, hb, l15, q);
        dense_layer(w3hi, w3lo, b3v4, hb, l15, q);

        // ---- output layer + decay-weighted accumulation ----
        {
            #pragma unroll
            for (int nh = 0; nh < 2; ++nh) {
                f32x4 co[2];
                co[0] = (f32x4){0.f, 0.f, 0.f, 0.f};
                co[1] = (f32x4){0.f, 0.f, 0.f, 0.f};
                #pragma unroll
                for (int ks = 0; ks < 2; ++ks) {
                    const f16x8 bf0 = *(const f16x8*)&hb[(nh * 2 + 0) * 16 + l15][ks * 32 + q * 8];
                    const f16x8 bf1 = *(const f16x8*)&hb[(nh * 2 + 1) * 16 + l15][ks * 32 + q * 8];
                    co[0] = mfma16h(wohi[ks], bf0, co[0]);
                    co[1] = mfma16h(wohi[ks], bf1, co[1]);
                    co[0] = mfma16h(wolo[ks], bf0, co[0]);
                    co[1] = mfma16h(wolo[ks], bf1, co[1]);
                }
                if (q == 0) {   // rows 0..2 of C = out0..2, live in lanes 0..15
                    #pragma unroll
                    for (int n = 0; n < 2; ++n) {
                        const int p = (nh * 2 + n) * 16 + l15;
                        const float4 g1 = *(const float4*)&geom[wv][p][0];
                        const float4 g2 = *(const float4*)&geom[wv][p][4];
                        const float o0 = co[n][0] + bo0;
                        const float o1 = co[n][1] + bo1;
                        const float o2 = co[n][2] + bo2;
                        accp = fmaf(o0, g1.x, accp);
                        avx  = fmaf(fmaf(o1, g1.y, o2 * g2.x), g1.x, avx);
                        avy  = fmaf(fmaf(o1, g1.z, o2 * g2.y), g1.x, avy);
                        avz  = fmaf(fmaf(o1, g1.w, o2 * g2.z), g1.x, avz);
                    }
                }
            }
        }
    }

    // ---- reduce across the 16 accumulating lanes ----
    #pragma unroll
    for (int off = 8; off > 0; off >>= 1) {
        accp += __shfl_down(accp, off);
        avx  += __shfl_down(avx,  off);
        avy  += __shfl_down(avy,  off);
        avz  += __shfl_down(avz,  off);
    }

    if (lane == 0) {
        const float ps = p_scale[0], pb = p_bias[0];
        const float vs = v_scale[0], vb = v_bias[0];
        out[4 * t + 0] = fmaf(accp, ps, pb);
        out[4 * t + 1] = fmaf(avx, vs, vb);
        out[4 * t + 2] = fmaf(avy, vs, vb);
        out[4 * t + 3] = fmaf(avz, vs, vb);
    }
}

extern "C" void kernel_launch(void* const* d_in, const int* in_sizes, int n_in,
                              void* d_out, int out_size, void* d_ws, size_t ws_size,
                              hipStream_t stream) {
    (void)in_sizes; (void)n_in; (void)d_ws; (void)ws_size; (void)out_size;
    const float* pts   = (const float*)d_in[0];
    const float* ctr   = (const float*)d_in[1];
    const float* nrm   = (const float*)d_in[2];
    const float* areas = (const float*)d_in[3];
    const float* rlen  = (const float*)d_in[4];
    const float* W1    = (const float*)d_in[5];
    const float* b1    = (const float*)d_in[6];
    const float* W2    = (const float*)d_in[7];
    const float* b2    = (const float*)d_in[8];
    const float* W3    = (const float*)d_in[9];
    const float* b3    = (const float*)d_in[10];
    const float* Wout  = (const float*)d_in[11];
    const float* bout  = (const float*)d_in[12];
    const float* ps    = (const float*)d_in[13];
    const float* pb    = (const float*)d_in[14];
    const float* vs    = (const float*)d_in[15];
    const float* vb    = (const float*)d_in[16];

    dim3 grid(N_T / WPB), block(BLK);
    globe_mfma<<<grid, block, 0, stream>>>(
        pts, ctr, nrm, areas, rlen, W1, b1, W2, b2, W3, b3, Wout, bout,
        ps, pb, vs, vb, (float*)d_out);
}